// Round 6
// baseline (5141.928 us; speedup 1.0000x reference)
//
#include <hip/hip_runtime.h>

#define H 64
#define T_STEPS 2048
#define SEQS 16          // sequences per block = B/D columns
#define SSTR 200         // per-seq S stride in halves (400 B: 16 mod 128 -> <=2-way banks)

typedef _Float16 f16x8 __attribute__((ext_vector_type(8)));
typedef float    f32x4 __attribute__((ext_vector_type(4)));

__device__ __forceinline__ float sig_f(float x) {
    return 1.0f / (1.0f + __expf(-x));
}
__device__ __forceinline__ float tanh_f(float x) {
    return 2.0f / (1.0f + __expf(-2.0f * x)) - 1.0f;
}

// load 8 consecutive f32 -> f16x8 (setup only)
__device__ __forceinline__ f16x8 ldcvt8(const float* __restrict__ p) {
    float4 a = ((const float4*)p)[0];
    float4 c = ((const float4*)p)[1];
    f16x8 r;
    r[0]=(_Float16)a.x; r[1]=(_Float16)a.y; r[2]=(_Float16)a.z; r[3]=(_Float16)a.w;
    r[4]=(_Float16)c.x; r[5]=(_Float16)c.y; r[6]=(_Float16)c.z; r[7]=(_Float16)c.w;
    return r;
}

#define MFMA(a, b, c) __builtin_amdgcn_mfma_f32_16x16x32_f16((a), (b), (c), 0, 0, 0)

// R19: 16 SEQUENCES PER BLOCK — B COLUMNS = SEQUENCES.
// Invariant found R16-R18: with 1 seq/block, B has 1 useful column of 16
// -> 160 MFMAs/step = 776 cyc MFMA-pipe floor + un-hideable act tail.
// The only independent work that can fill B's columns is other sequences.
// R19: block owns 16 seqs; col lj = seq. Same 160 MFMAs now serve 16
// seqs. D-frag of wave w lane l = all 4 gates (regs r=0..3) of
// (cell 4w+kg, seq lj) -> cell update runs UNMASKED ON ALL 64 LANES in
// registers: no gbuf, no act waves, no shuffles (R18's bpermute
// conflicts gone), ONE barrier/phase. Act co-issues with MFMA (separate
// pipes, m114). Grid = 16 blocks; wall is phase-bound, idle CUs free.
// Layer pipeline unchanged: L0 t=p, L1 t=p-1, L2 t=p-2; read slot
// (p+1)&1, write slot p&1, barrier at phase end.
__global__ __launch_bounds__(1024, 4)
void lstm3_r19(const float* __restrict__ x,
               const float* __restrict__ Wih0, const float* __restrict__ Whh0,
               const float* __restrict__ bih0, const float* __restrict__ bhh0,
               const float* __restrict__ Wih1, const float* __restrict__ Whh1,
               const float* __restrict__ bih1, const float* __restrict__ bhh1,
               const float* __restrict__ Wih2, const float* __restrict__ Whh2,
               const float* __restrict__ bih2, const float* __restrict__ bhh2,
               const float* __restrict__ Wout, const float* __restrict__ bout,
               float* __restrict__ out)
{
    // S[slot][seq][0:64 h0 | 64:128 h1 | 128:192 h2 | pad to 200]
    __shared__ __align__(16) _Float16 S[2][SEQS][SSTR];   // 12.8 KB
    __shared__ __align__(16) float h2f[SEQS][H];          // 4 KB

    const int tid  = threadIdx.x;
    const int w    = tid >> 6;           // wave 0..15 = M-tile (cells 4w..4w+3)
    const int l    = tid & 63;
    const int lj   = l & 15;             // seq-in-block / B,D column
    const int kg   = l >> 4;             // k-group / D row-quad
    const int cell = 4 * w + kg;         // cell this lane's D covers
    const int seq  = blockIdx.x * SEQS + lj;

    // ---- A-fragments (16x16x32 f16): A row = lj, k = kg*8+i. Permuted
    // M-row' = 16w+lj <-> cell 4w+(lj>>2), gate lj&3 (R16-proven).
    const int cellA = 4 * w + (lj >> 2);
    const int gateA = lj & 3;
    const int wrow  = gateA * H + cellA;
    const int kc    = kg * 8;

    f16x8 A00 = ldcvt8(Whh0 + wrow * H + kc);        // L0 <- h0 lo
    f16x8 A01 = ldcvt8(Whh0 + wrow * H + 32 + kc);   // L0 <- h0 hi
    f16x8 A10 = ldcvt8(Wih1 + wrow * H + kc);        // L1 <- h0 lo
    f16x8 A11 = ldcvt8(Wih1 + wrow * H + 32 + kc);   // L1 <- h0 hi
    f16x8 A12 = ldcvt8(Whh1 + wrow * H + kc);        // L1 <- h1 lo
    f16x8 A13 = ldcvt8(Whh1 + wrow * H + 32 + kc);   // L1 <- h1 hi
    f16x8 A20 = ldcvt8(Wih2 + wrow * H + kc);        // L2 <- h1 lo
    f16x8 A21 = ldcvt8(Wih2 + wrow * H + 32 + kc);   // L2 <- h1 hi
    f16x8 A22 = ldcvt8(Whh2 + wrow * H + kc);        // L2 <- h2 lo
    f16x8 A23 = ldcvt8(Whh2 + wrow * H + 32 + kc);   // L2 <- h2 hi
    // park in AGPRs once (outside loop; R16-proven pattern)
    asm volatile("" : "+a"(A00), "+a"(A01), "+a"(A10), "+a"(A11));
    asm volatile("" : "+a"(A12), "+a"(A13), "+a"(A20), "+a"(A21));
    asm volatile("" : "+a"(A22), "+a"(A23));

    // ---- per-lane cell constants: C-frag row r = gate r of `cell`,
    // col lj (same for all cols -> seq-independent biases; x-term is
    // per-col and folds per-lane since lane's col IS its seq).
    f32x4 cb0, cb1, cb2;
    float wx[8];
#pragma unroll
    for (int r = 0; r < 4; ++r) {
        cb0[r] = bih0[r * H + cell] + bhh0[r * H + cell];
        cb1[r] = bih1[r * H + cell] + bhh1[r * H + cell];
        cb2[r] = bih2[r * H + cell] + bhh2[r * H + cell];
        wx[2 * r]     = Wih0[(r * H + cell) * 2];
        wx[2 * r + 1] = Wih0[(r * H + cell) * 2 + 1];
    }
    float cst0 = 0.f, cst1 = 0.f, cst2 = 0.f;
    const float* xseq = x + (size_t)seq * T_STEPS * 2;

    // ---- zero S (both slots incl. pad): 3200 f32 ----
    for (int i = tid; i < (int)(sizeof(S) / 4); i += 1024)
        ((float*)S)[i] = 0.f;
    __syncthreads();

    const f32x4 z = {0.f, 0.f, 0.f, 0.f};

#pragma unroll 1
    for (int p = 0; p <= T_STEPS + 1; ++p) {
        const bool on0 = (p < T_STEPS);
        const bool on1 = (p >= 1) && (p <= T_STEPS);
        const bool on2 = (p >= 2);

        // x_t for this lane's seq (global; L1-hot; issued before MFMAs)
        const int px = on0 ? p : (T_STEPS - 1);
        float2 xt = *(const float2*)(xseq + 2 * px);

        // B-frags: lane holds col lj, k = kg*8+i of each 32-K chunk.
        // chunk c at seq-local bytes c*64; lane offset kg*16.
        const char* base = (const char*)&S[(p + 1) & 1][lj][0] + kg * 16;
        f16x8 b0 = *(const f16x8*)(base + 0);      // h0 lo
        f16x8 b1 = *(const f16x8*)(base + 64);     // h0 hi
        f16x8 b2 = *(const f16x8*)(base + 128);    // h1 lo
        f16x8 b3 = *(const f16x8*)(base + 192);    // h1 hi
        f16x8 b4 = *(const f16x8*)(base + 256);    // h2 lo
        f16x8 b5 = *(const f16x8*)(base + 320);    // h2 hi

        // L0 C-operand: bias + per-seq x-term
        f32x4 c0;
#pragma unroll
        for (int r = 0; r < 4; ++r)
            c0[r] = cb0[r] + wx[2 * r] * xt.x + wx[2 * r + 1] * xt.y;

        // ---- MFMAs (uniform branches; split accumulators) ----
        f32x4 g0, g1, g2;
        if (on0) { g0 = MFMA(A00, b0, c0);  g0 = MFMA(A01, b1, g0); }
        if (on1) {
            f32x4 ga = MFMA(A10, b0, cb1); ga = MFMA(A11, b1, ga);
            f32x4 gb = MFMA(A12, b2, z);   gb = MFMA(A13, b3, gb);
            g1 = ga + gb;
        }
        if (on2) {
            f32x4 gc = MFMA(A20, b2, cb2); gc = MFMA(A21, b3, gc);
            f32x4 gd = MFMA(A22, b4, z);   gd = MFMA(A23, b5, gd);
            g2 = gc + gd;
        }

        // ---- in-lane cell updates: ALL 64 lanes, no masks ----
        _Float16* Sw = &S[p & 1][lj][0];
        if (on0) {
            float i_ = sig_f(g0[0]), f_ = sig_f(g0[1]);
            float gg = tanh_f(g0[2]), o_ = sig_f(g0[3]);
            cst0 = f_ * cst0 + i_ * gg;
            Sw[cell] = (_Float16)(o_ * tanh_f(cst0));
        }
        if (on1) {
            float i_ = sig_f(g1[0]), f_ = sig_f(g1[1]);
            float gg = tanh_f(g1[2]), o_ = sig_f(g1[3]);
            cst1 = f_ * cst1 + i_ * gg;
            Sw[H + cell] = (_Float16)(o_ * tanh_f(cst1));
        }
        if (on2) {
            float i_ = sig_f(g2[0]), f_ = sig_f(g2[1]);
            float gg = tanh_f(g2[2]), o_ = sig_f(g2[3]);
            cst2 = f_ * cst2 + i_ * gg;
            float hh = o_ * tanh_f(cst2);
            Sw[2 * H + cell] = (_Float16)hh;
            if (p == T_STEPS + 1) h2f[lj][cell] = hh;   // final h2, f32
        }
        __syncthreads();
    }

    // ---- fused projection: out[seq,:] = h2_last @ Wout^T + bout ----
    if (tid < SEQS * 11) {
        const int sq = tid / 11, o = tid % 11;
        float acc = bout[o];
#pragma unroll
        for (int jj = 0; jj < H; ++jj)
            acc += Wout[o * H + jj] * h2f[sq][jj];
        out[(blockIdx.x * SEQS + sq) * 11 + o] = acc;
    }
}

extern "C" void kernel_launch(void* const* d_in, const int* in_sizes, int n_in,
                              void* d_out, int out_size, void* d_ws, size_t ws_size,
                              hipStream_t stream) {
    const float* x    = (const float*)d_in[0];
    const float* Wih0 = (const float*)d_in[1];
    const float* Whh0 = (const float*)d_in[2];
    const float* bih0 = (const float*)d_in[3];
    const float* bhh0 = (const float*)d_in[4];
    const float* Wih1 = (const float*)d_in[5];
    const float* Whh1 = (const float*)d_in[6];
    const float* bih1 = (const float*)d_in[7];
    const float* bhh1 = (const float*)d_in[8];
    const float* Wih2 = (const float*)d_in[9];
    const float* Whh2 = (const float*)d_in[10];
    const float* bih2 = (const float*)d_in[11];
    const float* bhh2 = (const float*)d_in[12];
    const float* Wout = (const float*)d_in[13];
    const float* bout = (const float*)d_in[14];
    float* out = (float*)d_out;

    lstm3_r19<<<16, 1024, 0, stream>>>(x,
        Wih0, Whh0, bih0, bhh0,
        Wih1, Whh1, bih1, bhh1,
        Wih2, Whh2, bih2, bhh2,
        Wout, bout, out);
}

// Round 7
// 3106.974 us; speedup vs baseline: 1.6550x; 1.6550x over previous
//
#include <hip/hip_runtime.h>

#define H 64
#define T_STEPS 2048
#define SEQS 16          // sequences per block = B/D columns
#define SSTR 200         // per-seq S stride in halves (400 B)

typedef _Float16 f16x8 __attribute__((ext_vector_type(8)));
typedef float    f32x4 __attribute__((ext_vector_type(4)));

// ---- RAW native transcendentals (R20): v_exp_f32 / v_rcp_f32 ----
// R13-R19 post-mortem: __expf + f32 division lowered to library exp +
// IEEE div sequences (~200-400 VALU-cyc per cell update) -> act was
// ~5100 cyc/SIMD/step, 4x the hand count, dominating every round.
__device__ __forceinline__ float fexp2(float x) {
#if __has_builtin(__builtin_amdgcn_exp2f)
    return __builtin_amdgcn_exp2f(x);
#else
    float r; asm("v_exp_f32 %0, %1" : "=v"(r) : "v"(x)); return r;
#endif
}
__device__ __forceinline__ float frcp(float x) {
#if __has_builtin(__builtin_amdgcn_rcpf)
    return __builtin_amdgcn_rcpf(x);
#else
    float r; asm("v_rcp_f32 %0, %1" : "=v"(r) : "v"(x)); return r;
#endif
}
// pre-acts arrive PRE-SCALED by -log2e (i,f,o) or -2log2e (g):
// sig(pre)  = rcp(1 + exp2(y)),          y = -log2e * pre
// tanh(pre) = 2*rcp(1 + exp2(y)) - 1,    y = -2log2e * pre
__device__ __forceinline__ float sig_y(float y) {
    return frcp(1.0f + fexp2(y));
}
__device__ __forceinline__ float tanh_y(float y) {
    return 2.0f * frcp(1.0f + fexp2(y)) - 1.0f;
}
#define NL2E  (-1.44269504088896341f)
#define N2L2E (-2.88539008177792681f)

// load 8 consecutive f32, scale, -> f16x8 (setup only)
__device__ __forceinline__ f16x8 ldcvt8s(const float* __restrict__ p, float s) {
    float4 a = ((const float4*)p)[0];
    float4 c = ((const float4*)p)[1];
    f16x8 r;
    r[0]=(_Float16)(s*a.x); r[1]=(_Float16)(s*a.y);
    r[2]=(_Float16)(s*a.z); r[3]=(_Float16)(s*a.w);
    r[4]=(_Float16)(s*c.x); r[5]=(_Float16)(s*c.y);
    r[6]=(_Float16)(s*c.z); r[7]=(_Float16)(s*c.w);
    return r;
}

#define MFMA(a, b, c) __builtin_amdgcn_mfma_f32_16x16x32_f16((a), (b), (c), 0, 0, 0)

// R20: R19's 16-seq MFMA structure + native-ISA activations.
// Structure recap (R19): block owns 16 seqs; B/D col lj = seq. Wave w's
// D-frag lane l = all 4 gates (regs 0..3) of (cell 4w+kg, seq lj) ->
// cell update unmasked on all 64 lanes, no shuffles, no gbuf, ONE
// barrier/phase. Weights in AGPRs, consumed by MFMA in place. Layer
// pipeline: L0 t=p, L1 t=p-1, L2 t=p-2; read slot (p+1)&1, write p&1.
// New in R20: gate rows of A/bias/x-weights pre-scaled by -log2e
// (-2log2e for g-rows) so each activation is exp2+add+rcp.
__global__ __launch_bounds__(1024, 4)
void lstm3_r20(const float* __restrict__ x,
               const float* __restrict__ Wih0, const float* __restrict__ Whh0,
               const float* __restrict__ bih0, const float* __restrict__ bhh0,
               const float* __restrict__ Wih1, const float* __restrict__ Whh1,
               const float* __restrict__ bih1, const float* __restrict__ bhh1,
               const float* __restrict__ Wih2, const float* __restrict__ Whh2,
               const float* __restrict__ bih2, const float* __restrict__ bhh2,
               const float* __restrict__ Wout, const float* __restrict__ bout,
               float* __restrict__ out)
{
    // S[slot][seq][0:64 h0 | 64:128 h1 | 128:192 h2 | pad to 200]
    __shared__ __align__(16) _Float16 S[2][SEQS][SSTR];   // 12.8 KB
    __shared__ __align__(16) float h2f[SEQS][H];          // 4 KB

    const int tid  = threadIdx.x;
    const int w    = tid >> 6;           // wave 0..15 = M-tile (cells 4w..4w+3)
    const int l    = tid & 63;
    const int lj   = l & 15;             // seq-in-block / B,D column
    const int kg   = l >> 4;             // k-group / D row-quad
    const int cell = 4 * w + kg;         // cell this lane's D covers
    const int seq  = blockIdx.x * SEQS + lj;

    // ---- A-fragments: A row = lj, k = kg*8+i. Permuted M-row' = 16w+lj
    // <-> cell 4w+(lj>>2), gate lj&3 (R16-proven). Row scale by gate.
    const int cellA = 4 * w + (lj >> 2);
    const int gateA = lj & 3;
    const int wrow  = gateA * H + cellA;
    const int kc    = kg * 8;
    const float sA  = (gateA == 2) ? N2L2E : NL2E;

    f16x8 A00 = ldcvt8s(Whh0 + wrow * H + kc,      sA);   // L0 <- h0 lo
    f16x8 A01 = ldcvt8s(Whh0 + wrow * H + 32 + kc, sA);   // L0 <- h0 hi
    f16x8 A10 = ldcvt8s(Wih1 + wrow * H + kc,      sA);   // L1 <- h0 lo
    f16x8 A11 = ldcvt8s(Wih1 + wrow * H + 32 + kc, sA);   // L1 <- h0 hi
    f16x8 A12 = ldcvt8s(Whh1 + wrow * H + kc,      sA);   // L1 <- h1 lo
    f16x8 A13 = ldcvt8s(Whh1 + wrow * H + 32 + kc, sA);   // L1 <- h1 hi
    f16x8 A20 = ldcvt8s(Wih2 + wrow * H + kc,      sA);   // L2 <- h1 lo
    f16x8 A21 = ldcvt8s(Wih2 + wrow * H + 32 + kc, sA);   // L2 <- h1 hi
    f16x8 A22 = ldcvt8s(Whh2 + wrow * H + kc,      sA);   // L2 <- h2 lo
    f16x8 A23 = ldcvt8s(Whh2 + wrow * H + 32 + kc, sA);   // L2 <- h2 hi
    // park in AGPRs once (outside loop; R16-proven pattern)
    asm volatile("" : "+a"(A00), "+a"(A01), "+a"(A10), "+a"(A11));
    asm volatile("" : "+a"(A12), "+a"(A13), "+a"(A20), "+a"(A21));
    asm volatile("" : "+a"(A22), "+a"(A23));

    // ---- per-lane cell constants (C-frag row r = gate r of `cell`),
    // scaled per gate row: r==2 -> -2log2e else -log2e.
    f32x4 cb0, cb1, cb2;
    float wx[8];
#pragma unroll
    for (int r = 0; r < 4; ++r) {
        const float sr = (r == 2) ? N2L2E : NL2E;
        cb0[r] = sr * (bih0[r * H + cell] + bhh0[r * H + cell]);
        cb1[r] = sr * (bih1[r * H + cell] + bhh1[r * H + cell]);
        cb2[r] = sr * (bih2[r * H + cell] + bhh2[r * H + cell]);
        wx[2 * r]     = sr * Wih0[(r * H + cell) * 2];
        wx[2 * r + 1] = sr * Wih0[(r * H + cell) * 2 + 1];
    }
    float cst0 = 0.f, cst1 = 0.f, cst2 = 0.f;
    const float* xseq = x + (size_t)seq * T_STEPS * 2;

    // ---- zero S (both slots incl. pad) ----
    for (int i = tid; i < (int)(sizeof(S) / 4); i += 1024)
        ((float*)S)[i] = 0.f;
    __syncthreads();

    const f32x4 z = {0.f, 0.f, 0.f, 0.f};

#pragma unroll 1
    for (int p = 0; p <= T_STEPS + 1; ++p) {
        const bool on0 = (p < T_STEPS);
        const bool on1 = (p >= 1) && (p <= T_STEPS);
        const bool on2 = (p >= 2);

        // x_t for this lane's seq (global; L1-hot; issued before MFMAs)
        const int px = on0 ? p : (T_STEPS - 1);
        float2 xt = *(const float2*)(xseq + 2 * px);

        // B-frags: lane holds col lj, k = kg*8+i of each 32-K chunk.
        const char* base = (const char*)&S[(p + 1) & 1][lj][0] + kg * 16;
        f16x8 b0 = *(const f16x8*)(base + 0);      // h0 lo
        f16x8 b1 = *(const f16x8*)(base + 64);     // h0 hi
        f16x8 b2 = *(const f16x8*)(base + 128);    // h1 lo
        f16x8 b3 = *(const f16x8*)(base + 192);    // h1 hi
        f16x8 b4 = *(const f16x8*)(base + 256);    // h2 lo
        f16x8 b5 = *(const f16x8*)(base + 320);    // h2 hi

        // L0 C-operand: scaled bias + scaled per-seq x-term
        f32x4 c0;
#pragma unroll
        for (int r = 0; r < 4; ++r)
            c0[r] = cb0[r] + wx[2 * r] * xt.x + wx[2 * r + 1] * xt.y;

        // ---- MFMAs (uniform branches; split accumulators) ----
        f32x4 g0, g1, g2;
        if (on0) { g0 = MFMA(A00, b0, c0);  g0 = MFMA(A01, b1, g0); }
        if (on1) {
            f32x4 ga = MFMA(A10, b0, cb1); ga = MFMA(A11, b1, ga);
            f32x4 gb = MFMA(A12, b2, z);   gb = MFMA(A13, b3, gb);
            g1 = ga + gb;
        }
        if (on2) {
            f32x4 gc = MFMA(A20, b2, cb2); gc = MFMA(A21, b3, gc);
            f32x4 gd = MFMA(A22, b4, z);   gd = MFMA(A23, b5, gd);
            g2 = gc + gd;
        }

        // ---- in-lane cell updates: ALL 64 lanes, native trans ----
        _Float16* Sw = &S[p & 1][lj][0];
        if (on0) {
            float i_ = sig_y(g0[0]), f_ = sig_y(g0[1]);
            float gg = tanh_y(g0[2]), o_ = sig_y(g0[3]);
            cst0 = f_ * cst0 + i_ * gg;
            Sw[cell] = (_Float16)(o_ * tanh_y(N2L2E * cst0));
        }
        if (on1) {
            float i_ = sig_y(g1[0]), f_ = sig_y(g1[1]);
            float gg = tanh_y(g1[2]), o_ = sig_y(g1[3]);
            cst1 = f_ * cst1 + i_ * gg;
            Sw[H + cell] = (_Float16)(o_ * tanh_y(N2L2E * cst1));
        }
        if (on2) {
            float i_ = sig_y(g2[0]), f_ = sig_y(g2[1]);
            float gg = tanh_y(g2[2]), o_ = sig_y(g2[3]);
            cst2 = f_ * cst2 + i_ * gg;
            float hh = o_ * tanh_y(N2L2E * cst2);
            Sw[2 * H + cell] = (_Float16)hh;
            if (p == T_STEPS + 1) h2f[lj][cell] = hh;   // final h2, f32
        }
        __syncthreads();
    }

    // ---- fused projection: out[seq,:] = h2_last @ Wout^T + bout ----
    if (tid < SEQS * 11) {
        const int sq = tid / 11, o = tid % 11;
        float acc = bout[o];
#pragma unroll
        for (int jj = 0; jj < H; ++jj)
            acc += Wout[o * H + jj] * h2f[sq][jj];
        out[(blockIdx.x * SEQS + sq) * 11 + o] = acc;
    }
}

extern "C" void kernel_launch(void* const* d_in, const int* in_sizes, int n_in,
                              void* d_out, int out_size, void* d_ws, size_t ws_size,
                              hipStream_t stream) {
    const float* x    = (const float*)d_in[0];
    const float* Wih0 = (const float*)d_in[1];
    const float* Whh0 = (const float*)d_in[2];
    const float* bih0 = (const float*)d_in[3];
    const float* bhh0 = (const float*)d_in[4];
    const float* Wih1 = (const float*)d_in[5];
    const float* Whh1 = (const float*)d_in[6];
    const float* bih1 = (const float*)d_in[7];
    const float* bhh1 = (const float*)d_in[8];
    const float* Wih2 = (const float*)d_in[9];
    const float* Whh2 = (const float*)d_in[10];
    const float* bih2 = (const float*)d_in[11];
    const float* bhh2 = (const float*)d_in[12];
    const float* Wout = (const float*)d_in[13];
    const float* bout = (const float*)d_in[14];
    float* out = (float*)d_out;

    lstm3_r20<<<16, 1024, 0, stream>>>(x,
        Wih0, Whh0, bih0, bhh0,
        Wih1, Whh1, bih1, bhh1,
        Wih2, Whh2, bih2, bhh2,
        Wout, bout, out);
}

// Round 8
// 2310.372 us; speedup vs baseline: 2.2256x; 1.3448x over previous
//
#include <hip/hip_runtime.h>

#define H 64
#define T_STEPS 2048
#define SEQS 4           // sequences per block; seq s rides MFMA column 4s
#define CHB 1024         // chunk bytes: [kg:4][col:16][8 halves]

typedef _Float16 f16x8 __attribute__((ext_vector_type(8)));
typedef float    f32x4 __attribute__((ext_vector_type(4)));

// ---- native transcendentals (R20-proven): v_exp_f32 / v_rcp_f32 ----
__device__ __forceinline__ float fexp2(float x) {
#if __has_builtin(__builtin_amdgcn_exp2f)
    return __builtin_amdgcn_exp2f(x);
#else
    float r; asm("v_exp_f32 %0, %1" : "=v"(r) : "v"(x)); return r;
#endif
}
__device__ __forceinline__ float frcp(float x) {
#if __has_builtin(__builtin_amdgcn_rcpf)
    return __builtin_amdgcn_rcpf(x);
#else
    float r; asm("v_rcp_f32 %0, %1" : "=v"(r) : "v"(x)); return r;
#endif
}
// pre-acts arrive PRE-SCALED by -log2e (i,f,o rows) / -2log2e (g rows)
__device__ __forceinline__ float sig_y(float y)  { return frcp(1.0f + fexp2(y)); }
__device__ __forceinline__ float tanh_y(float y) { return 2.0f * frcp(1.0f + fexp2(y)) - 1.0f; }
#define NL2E  (-1.44269504088896341f)
#define N2L2E (-2.88539008177792681f)

// load 8 consecutive f32, scale, -> f16x8 (setup only)
__device__ __forceinline__ f16x8 ldcvt8s(const float* __restrict__ p, float s) {
    float4 a = ((const float4*)p)[0];
    float4 c = ((const float4*)p)[1];
    f16x8 r;
    r[0]=(_Float16)(s*a.x); r[1]=(_Float16)(s*a.y);
    r[2]=(_Float16)(s*a.z); r[3]=(_Float16)(s*a.w);
    r[4]=(_Float16)(s*c.x); r[5]=(_Float16)(s*c.y);
    r[6]=(_Float16)(s*c.z); r[7]=(_Float16)(s*c.w);
    return r;
}

#define MFMA(a, b, c) __builtin_amdgcn_mfma_f32_16x16x32_f16((a), (b), (c), 0, 0, 0)

// R21: SEQS=4 x 64 BLOCKS — ONE ACT ROUND, QUAD-PERM REDISTRIBUTION,
// CONFLICT-FREE LDS CHUNKS.
// R20 post-mortem: trans issue ~16 cyc/wave64; SEQS=16 => 3 updates/lane
// = 30 trans-instr/wave/step = 1920 cyc/SIMD — a per-CU floor. Fix:
// spread the batch over 4x the CUs (grid 64, SEQS=4) and give each wave
// ONE act round: seq s on MFMA col 4s; lane (kg,lj) act role: layer
// u=lj&3 (u==3 idle), seq lj>>2, cell 4w+kg. L1/L2 frags arrive via
// __shfl_xor(.,1)/(.,2) = DPP quad_perm (full-rate; NOT R18's bpermute).
// State chunks [c][kg][col][8] make the 6 ds_read_b128 per wave land at
// base + lane*16 (sequential, zero conflicts; R20's layout was 8-way).
// Unused cols stay zero. MFMA structure unchanged (R16-validated):
// weights AGPR-parked, biases ride C, L0 t=p / L1 t=p-1 / L2 t=p-2,
// read slot (p+1)&1, write slot p&1, one barrier.
__global__ __launch_bounds__(1024, 4)
void lstm3_r21(const float* __restrict__ x,
               const float* __restrict__ Wih0, const float* __restrict__ Whh0,
               const float* __restrict__ bih0, const float* __restrict__ bhh0,
               const float* __restrict__ Wih1, const float* __restrict__ Whh1,
               const float* __restrict__ bih1, const float* __restrict__ bhh1,
               const float* __restrict__ Wih2, const float* __restrict__ Whh2,
               const float* __restrict__ bih2, const float* __restrict__ bhh2,
               const float* __restrict__ Wout, const float* __restrict__ bout,
               float* __restrict__ out)
{
    // state: 2 slots x 6 K-chunks x 1024 B; chunk = [kg][col][8 halves]
    __shared__ __align__(16) _Float16 S[2][6][512];       // 12 KB
    __shared__ __align__(16) float h2f[SEQS][H];          // 1 KB

    const int tid  = threadIdx.x;
    const int w    = tid >> 6;           // wave 0..15 = M-tile
    const int l    = tid & 63;
    const int lj   = l & 15;             // A row-in-tile / B,D column
    const int kg   = l >> 4;             // k-group / D row-quad
    const int cell = 4 * w + kg;         // cell of this lane's D rows
    const int u    = lj & 3;             // act role: layer (3 = idle)
    const int sq   = lj >> 2;            // act role: seq in block
    const int seqx = blockIdx.x * SEQS + sq;

    // ---- A-fragments (R16-proven mapping), pre-scaled by gate row ----
    const int cellA = 4 * w + (lj >> 2);
    const int gateA = lj & 3;
    const int wrow  = gateA * H + cellA;
    const int kc    = kg * 8;
    const float sA  = (gateA == 2) ? N2L2E : NL2E;

    f16x8 A00 = ldcvt8s(Whh0 + wrow * H + kc,      sA);   // L0 <- h0 lo
    f16x8 A01 = ldcvt8s(Whh0 + wrow * H + 32 + kc, sA);   // L0 <- h0 hi
    f16x8 A10 = ldcvt8s(Wih1 + wrow * H + kc,      sA);   // L1 <- h0 lo
    f16x8 A11 = ldcvt8s(Wih1 + wrow * H + 32 + kc, sA);   // L1 <- h0 hi
    f16x8 A12 = ldcvt8s(Whh1 + wrow * H + kc,      sA);   // L1 <- h1 lo
    f16x8 A13 = ldcvt8s(Whh1 + wrow * H + 32 + kc, sA);   // L1 <- h1 hi
    f16x8 A20 = ldcvt8s(Wih2 + wrow * H + kc,      sA);   // L2 <- h1 lo
    f16x8 A21 = ldcvt8s(Wih2 + wrow * H + 32 + kc, sA);   // L2 <- h1 hi
    f16x8 A22 = ldcvt8s(Whh2 + wrow * H + kc,      sA);   // L2 <- h2 lo
    f16x8 A23 = ldcvt8s(Whh2 + wrow * H + 32 + kc, sA);   // L2 <- h2 hi
    asm volatile("" : "+a"(A00), "+a"(A01), "+a"(A10), "+a"(A11));
    asm volatile("" : "+a"(A12), "+a"(A13), "+a"(A20), "+a"(A21));
    asm volatile("" : "+a"(A22), "+a"(A23));

    // ---- C-operand bias frags (indexed by this lane's D cell) ----
    f32x4 cb0, cb1, cb2;
    float wx[8];
#pragma unroll
    for (int r = 0; r < 4; ++r) {
        const float sr = (r == 2) ? N2L2E : NL2E;
        cb0[r] = sr * (bih0[r * H + cell] + bhh0[r * H + cell]);
        cb1[r] = sr * (bih1[r * H + cell] + bhh1[r * H + cell]);
        cb2[r] = sr * (bih2[r * H + cell] + bhh2[r * H + cell]);
        wx[2 * r]     = sr * Wih0[(r * H + cell) * 2];
        wx[2 * r + 1] = sr * Wih0[(r * H + cell) * 2 + 1];
    }
    float cst = 0.f;                     // state of this lane's act role
    const float* xseq = x + (size_t)seqx * T_STEPS * 2;

    // ---- zero S (both slots; unused cols stay zero forever) ----
    for (int i = tid; i < (int)(sizeof(S) / 4); i += 1024)
        ((float*)S)[i] = 0.f;
    __syncthreads();

    const f32x4 z = {0.f, 0.f, 0.f, 0.f};

#pragma unroll 1
    for (int p = 0; p <= T_STEPS + 1; ++p) {
        const bool on0 = (p < T_STEPS);
        const bool on1 = (p >= 1) && (p <= T_STEPS);
        const bool on2 = (p >= 2);

        // x_t (4 lanes/seq load the same 8B; L1 broadcast)
        const int px = on0 ? p : (T_STEPS - 1);
        float2 xt = *(const float2*)(xseq + 2 * px);

        // B-frags: 6 sequential b128, addr = slotbase + lane*16 (0-conflict)
        const char* base = (const char*)S + ((p + 1) & 1) * (6 * CHB)
                         + (size_t)l * 16;
        f16x8 b0 = *(const f16x8*)(base + 0 * CHB);   // h0 lo
        f16x8 b1 = *(const f16x8*)(base + 1 * CHB);   // h0 hi
        f16x8 b2 = *(const f16x8*)(base + 2 * CHB);   // h1 lo
        f16x8 b3 = *(const f16x8*)(base + 3 * CHB);   // h1 hi
        f16x8 b4 = *(const f16x8*)(base + 4 * CHB);   // h2 lo
        f16x8 b5 = *(const f16x8*)(base + 5 * CHB);   // h2 hi

        // L0 C-operand: scaled bias + per-col x-term
        f32x4 c0;
#pragma unroll
        for (int r = 0; r < 4; ++r)
            c0[r] = cb0[r] + wx[2 * r] * xt.x + wx[2 * r + 1] * xt.y;

        // ---- 10 MFMAs (biases ride C; split accumulators) ----
        f32x4 g0 = z, g1 = z, g2 = z;
        if (on0) { g0 = MFMA(A00, b0, c0);  g0 = MFMA(A01, b1, g0); }
        if (on1) {
            f32x4 ga = MFMA(A10, b0, cb1); ga = MFMA(A11, b1, ga);
            f32x4 gb = MFMA(A12, b2, z);   gb = MFMA(A13, b3, gb);
            g1 = ga + gb;
        }
        if (on2) {
            f32x4 gc = MFMA(A20, b2, cb2); gc = MFMA(A21, b3, gc);
            f32x4 gd = MFMA(A22, b4, z);   gd = MFMA(A23, b5, gd);
            g2 = gc + gd;
        }

        // ---- redistribute L1/L2 frags to act lanes: quad-perm DPP ----
        f32x4 g1s, g2s;
#pragma unroll
        for (int r = 0; r < 4; ++r) {
            g1s[r] = __shfl_xor(g1[r], 1);   // u==1 lane <- u==0 lane
            g2s[r] = __shfl_xor(g2[r], 2);   // u==2 lane <- u==0 lane
        }

        // ---- ONE act round: lane role (u, sq, cell) ----
        f32x4 pre = (u == 0) ? g0 : (u == 1) ? g1s : g2s;
        const bool act_on = (u == 0) ? on0 : (u == 1) ? on1
                          : (u == 2) ? on2 : false;
        float i_ = sig_y(pre[0]), f_ = sig_y(pre[1]);
        float gg = tanh_y(pre[2]), o_ = sig_y(pre[3]);
        float cn = f_ * cst + i_ * gg;
        float hh = o_ * tanh_y(N2L2E * cn);
        if (act_on) {
            cst = cn;
            const int k = u * 64 + cell;         // K-position of this h
            _Float16* Sw = (_Float16*)((char*)S + (p & 1) * (6 * CHB)
                          + (k >> 5) * CHB + ((k & 31) >> 3) * 256
                          + sq * 64 + (k & 7) * 2);
            *Sw = (_Float16)hh;
            if (u == 2 && p == T_STEPS + 1) h2f[sq][cell] = hh;  // final h2
        }
        __syncthreads();
    }

    // ---- fused projection: out[seq,:] = h2_last @ Wout^T + bout ----
    if (tid < SEQS * 11) {
        const int sq2 = tid / 11, o = tid % 11;
        float acc = bout[o];
#pragma unroll
        for (int jj = 0; jj < H; ++jj)
            acc += Wout[o * H + jj] * h2f[sq2][jj];
        out[(blockIdx.x * SEQS + sq2) * 11 + o] = acc;
    }
}

extern "C" void kernel_launch(void* const* d_in, const int* in_sizes, int n_in,
                              void* d_out, int out_size, void* d_ws, size_t ws_size,
                              hipStream_t stream) {
    const float* x    = (const float*)d_in[0];
    const float* Wih0 = (const float*)d_in[1];
    const float* Whh0 = (const float*)d_in[2];
    const float* bih0 = (const float*)d_in[3];
    const float* bhh0 = (const float*)d_in[4];
    const float* Wih1 = (const float*)d_in[5];
    const float* Whh1 = (const float*)d_in[6];
    const float* bih1 = (const float*)d_in[7];
    const float* bhh1 = (const float*)d_in[8];
    const float* Wih2 = (const float*)d_in[9];
    const float* Whh2 = (const float*)d_in[10];
    const float* bih2 = (const float*)d_in[11];
    const float* bhh2 = (const float*)d_in[12];
    const float* Wout = (const float*)d_in[13];
    const float* bout = (const float*)d_in[14];
    float* out = (float*)d_out;

    lstm3_r21<<<64, 1024, 0, stream>>>(x,
        Wih0, Whh0, bih0, bhh0,
        Wih1, Whh1, bih1, bhh1,
        Wih2, Whh2, bih2, bhh2,
        Wout, bout, out);
}